// Round 4
// baseline (101.167 us; speedup 1.0000x reference)
//
#include <hip/hip_runtime.h>

// SSIM-1D fused: 5 depthwise convs (K=11, zero-pad 5) + rational epilogue.
// R4: packed-fp32 via v_pk_fma_f32 with all-VGPR operands (R3's SGPR+op_sel_hi
// form doesn't assemble on gfx950). 6 distinct weights (symmetric filter) are
// materialized as {w,w} VGPR pairs once. Conv inner loop: 2 pk_fma + 1 fma
// per tap (was 5 fma). Window footprint halved vs scalar version.

typedef float f2 __attribute__((ext_vector_type(2)));

constexpr int K = 11;
constexpr int OPT = 8;           // outputs per thread
constexpr int BLK = 256;         // threads per block
constexpr int CHUNK = OPT * BLK; // 2048 row elements per block

__device__ __forceinline__ void pk_fma(f2& acc, f2 w, f2 x) {
    asm("v_pk_fma_f32 %0, %1, %2, %0" : "+v"(acc) : "v"(w), "v"(x));
}
__device__ __forceinline__ f2 pk_mul(f2 a, f2 b) {
    f2 d;
    asm("v_pk_mul_f32 %0, %1, %2" : "=v"(d) : "v"(a), "v"(b));
    return d;
}

__global__ __launch_bounds__(BLK, 4) void ssim1d_kernel(
    const float* __restrict__ s1, const float* __restrict__ s2,
    float* __restrict__ out, int N)
{
    const int tid   = threadIdx.x;
    const int bid   = blockIdx.x;
    const int chunks_per_row = N / CHUNK;
    const int chunk = bid % chunks_per_row;
    const int row   = bid / chunks_per_row;
    const int base  = chunk * CHUNK + tid * OPT;
    const size_t rowoff = (size_t)row * (size_t)N;
    const float* r1 = s1 + rowoff;
    const float* r2 = s2 + rowoff;

    // Gaussian(11, 1.5) normalized (matches numpy float32 to ~1e-7).
    const float W[6] = {0.00102838f, 0.00759876f, 0.03600079f,
                        0.10936070f, 0.21300553f, 0.26601172f};
    // Scalar weights per tap (SGPR — legal as the one scalar operand of v_fma).
    const float Wt[K] = {W[0], W[1], W[2], W[3], W[4], W[5],
                         W[4], W[3], W[2], W[1], W[0]};
    // Packed {w,w} VGPR pairs for pk_fma (all-VGPR form).
    f2 Wv[6];
#pragma unroll
    for (int i = 0; i < 6; ++i) Wv[i] = f2{W[i], W[i]};

    // Load 24-float aligned window [base-8, base+16); needed is [base-5, base+13).
    float t1[24], t2[24];
    if (base >= 8 && base <= N - 16) {
#pragma unroll
        for (int i = 0; i < 6; ++i) {
            *(float4*)&t1[4 * i] = *(const float4*)(r1 + base - 8 + 4 * i);
            *(float4*)&t2[4 * i] = *(const float4*)(r2 + base - 8 + 4 * i);
        }
    } else {
        // Row-edge slow path (2 threads per row): zero-fill outside [0, N).
#pragma unroll
        for (int j = 0; j < 24; ++j) {
            int idx = base - 8 + j;
            bool ok = (idx >= 0) && (idx < N);
            t1[j] = ok ? r1[idx] : 0.0f;
            t2[j] = ok ? r2[idx] : 0.0f;
        }
    }

    // Pair the two signals: window element m (row pos base-5+m) -> p[m].
    f2 p[18];
#pragma unroll
    for (int m = 0; m < 18; ++m) p[m] = f2{t1[m + 3], t2[m + 3]};

    // Packed squares + scalar cross products, once per window element.
    f2 qp[18];
    float q12[18];
#pragma unroll
    for (int m = 0; m < 18; ++m) {
        qp[m]  = pk_mul(p[m], p[m]);  // {t1^2, t2^2}
        q12[m] = p[m].x * p[m].y;     // t1*t2
    }

    const float C1 = 1.0e-4f;   // (0.01*VAL_RANGE)^2
    const float C2 = 9.0e-4f;   // (0.03*VAL_RANGE)^2

    float res[OPT];
#pragma unroll
    for (int j = 0; j < OPT; ++j) {
        f2 mu = {0.f, 0.f};   // {mu1, mu2}
        f2 ms = {0.f, 0.f};   // {E[s1^2], E[s2^2]}
        float m12 = 0.f;      // E[s1*s2]
#pragma unroll
        for (int k = 0; k < K; ++k) {
            const int wi = (k < 6) ? k : 10 - k;  // symmetric filter
            pk_fma(mu, Wv[wi], p[j + k]);
            pk_fma(ms, Wv[wi], qp[j + k]);
            m12 = fmaf(Wt[k], q12[j + k], m12);
        }
        f2 musq = pk_mul(mu, mu);          // {mu1^2, mu2^2}
        float mu12 = mu.x * mu.y;
        f2 sp = ms - musq;                 // {sigma1^2, sigma2^2}
        float s12 = m12 - mu12;
        float num = fmaf(2.f, mu12, C1) * fmaf(2.f, s12, C2);
        float den = (musq.x + musq.y + C1) * (sp.x + sp.y + C2);
        float ssim = num * __builtin_amdgcn_rcpf(den);  // den >= C1*C2 > 0
        res[j] = 0.5f - 0.5f * ssim;                    // 1 - (ssim+1)/2
    }

    float* o = out + rowoff + base;
    *(float4*)&o[0] = *(float4*)&res[0];
    *(float4*)&o[4] = *(float4*)&res[4];
}

extern "C" void kernel_launch(void* const* d_in, const int* in_sizes, int n_in,
                              void* d_out, int out_size, void* d_ws, size_t ws_size,
                              hipStream_t stream) {
    const float* s1 = (const float*)d_in[0];
    const float* s2 = (const float*)d_in[1];
    float* out = (float*)d_out;

    const int N = 4096;                 // row length per reference
    const int total = in_sizes[0];      // B * N
    const int B = total / N;
    const int blocks = B * (N / CHUNK); // 8192 * 2 = 16384

    ssim1d_kernel<<<blocks, BLK, 0, stream>>>(s1, s2, out, N);
}

// Round 6
// 94.795 us; speedup vs baseline: 1.0672x; 1.0672x over previous
//
#include <hip/hip_runtime.h>

// SSIM-1D fused: 5 depthwise convs (K=11, zero-pad 5) + rational epilogue.
// R6: 2-phase LDS pipeline with FULL-WAVE UNPREDICATED global_load_lds only
// (R5's lane-predicated tail DMA is the suspected corruption source: HW
// writes base+lane*16 per wave, exec-masked DMA is unverified). Each chunk
// stages exactly 2048 floats/signal = 2 full-wave 16B DMA rounds/signal.
// Halos are NOT staged: tid 0 / tid 255 patch their outer 8 window floats
// from global (L2-hot) or zero them at row edges. Double-buffered, one
// __syncthreads per chunk (drains vmcnt), 8 rows/block -> 1024 blocks.

typedef float f4 __attribute__((ext_vector_type(4)));

constexpr int K = 11;
constexpr int OPT = 8;            // outputs per thread
constexpr int BLK = 256;          // threads per block
constexpr int CHUNK = OPT * BLK;  // 2048
constexpr int N_FIXED = 4096;
constexpr int CPR = N_FIXED / CHUNK;  // 2 chunks per row
constexpr int RPB = 8;                // rows per block
constexpr int NCHUNK = RPB * CPR;     // 16 chunk-iterations per block

__device__ __forceinline__ void stage_chunk(
    float* dst0, float* dst1,
    const float* __restrict__ s1, const float* __restrict__ s2,
    long cs, int tid)
{
    // 2048 floats per signal = 512 slabs; 2 full-wave DMA rounds per signal.
#pragma unroll
    for (int r = 0; r < 2; ++r) {
        const int s = tid + r * BLK;
        __builtin_amdgcn_global_load_lds(
            (const __attribute__((address_space(1))) void*)(s1 + cs + (long)s * 4),
            (__attribute__((address_space(3))) void*)(dst0 + s * 4), 16, 0, 0);
        __builtin_amdgcn_global_load_lds(
            (const __attribute__((address_space(1))) void*)(s2 + cs + (long)s * 4),
            (__attribute__((address_space(3))) void*)(dst1 + s * 4), 16, 0, 0);
    }
}

__device__ __forceinline__ void compute_chunk(
    const float* lds0, const float* lds1,
    const float* __restrict__ s1, const float* __restrict__ s2,
    float* __restrict__ out, long cs, int tid, int left_edge, int right_edge)
{
    // Window mapping: t[i] <-> global position cs + tid*8 - 8 + i, i = 0..23.
    float t1[24], t2[24];
    if (tid == 0) {
#pragma unroll
        for (int i = 0; i < 4; ++i) {
            *(f4*)&t1[8 + 4 * i] = *(const f4*)&lds0[4 * i];
            *(f4*)&t2[8 + 4 * i] = *(const f4*)&lds1[4 * i];
        }
        if (left_edge) {
#pragma unroll
            for (int j = 0; j < 8; ++j) { t1[j] = 0.f; t2[j] = 0.f; }
        } else {
            *(f4*)&t1[0] = *(const f4*)(s1 + cs - 8);
            *(f4*)&t1[4] = *(const f4*)(s1 + cs - 4);
            *(f4*)&t2[0] = *(const f4*)(s2 + cs - 8);
            *(f4*)&t2[4] = *(const f4*)(s2 + cs - 4);
        }
    } else if (tid == BLK - 1) {
#pragma unroll
        for (int i = 0; i < 4; ++i) {
            *(f4*)&t1[4 * i] = *(const f4*)&lds0[CHUNK - 16 + 4 * i];
            *(f4*)&t2[4 * i] = *(const f4*)&lds1[CHUNK - 16 + 4 * i];
        }
        if (right_edge) {
#pragma unroll
            for (int j = 16; j < 24; ++j) { t1[j] = 0.f; t2[j] = 0.f; }
        } else {
            *(f4*)&t1[16] = *(const f4*)(s1 + cs + CHUNK);
            *(f4*)&t1[20] = *(const f4*)(s1 + cs + CHUNK + 4);
            *(f4*)&t2[16] = *(const f4*)(s2 + cs + CHUNK);
            *(f4*)&t2[20] = *(const f4*)(s2 + cs + CHUNK + 4);
        }
    } else {
        const int o2 = tid * OPT - 8;
#pragma unroll
        for (int i = 0; i < 6; ++i) {
            *(f4*)&t1[4 * i] = *(const f4*)&lds0[o2 + 4 * i];
            *(f4*)&t2[4 * i] = *(const f4*)&lds1[o2 + 4 * i];
        }
    }

    // Squares / cross products once per window element (t[m+3] = pos rel -5+m).
    float q1[18], q2[18], q12[18];
#pragma unroll
    for (int m = 0; m < 18; ++m) {
        float a = t1[m + 3], b = t2[m + 3];
        q1[m] = a * a; q2[m] = b * b; q12[m] = a * b;
    }

    // Gaussian(11, 1.5) normalized (matches numpy float32 to ~1e-7); SGPR consts.
    const float Wt[K] = {0.00102838f, 0.00759876f, 0.03600079f, 0.10936070f,
                         0.21300553f, 0.26601172f, 0.21300553f, 0.10936070f,
                         0.03600079f, 0.00759876f, 0.00102838f};
    const float C1 = 1.0e-4f, C2 = 9.0e-4f;

    float res[OPT];
#pragma unroll
    for (int j = 0; j < OPT; ++j) {
        float mu1 = 0.f, mu2 = 0.f, m11 = 0.f, m22 = 0.f, m12 = 0.f;
#pragma unroll
        for (int k = 0; k < K; ++k) {
            float w = Wt[k];
            mu1 = fmaf(w, t1[j + k + 3], mu1);
            mu2 = fmaf(w, t2[j + k + 3], mu2);
            m11 = fmaf(w, q1[j + k], m11);
            m22 = fmaf(w, q2[j + k], m22);
            m12 = fmaf(w, q12[j + k], m12);
        }
        float mu1sq = mu1 * mu1;
        float mu2sq = mu2 * mu2;
        float mu12  = mu1 * mu2;
        float s11 = m11 - mu1sq;
        float s22 = m22 - mu2sq;
        float s12 = m12 - mu12;
        float num = fmaf(2.f, mu12, C1) * fmaf(2.f, s12, C2);
        float den = (mu1sq + mu2sq + C1) * (s11 + s22 + C2);
        float ssim = num * __builtin_amdgcn_rcpf(den);  // den >= C1*C2 > 0
        res[j] = 0.5f - 0.5f * ssim;                    // 1 - (ssim+1)/2
    }

    f4* op = (f4*)(out + cs + tid * OPT);
    op[0] = *(f4*)&res[0];
    op[1] = *(f4*)&res[4];
}

__global__ __launch_bounds__(BLK, 4) void ssim1d_kernel(
    const float* __restrict__ s1, const float* __restrict__ s2,
    float* __restrict__ out)
{
    __shared__ float lds[2][2][CHUNK];   // [buf][signal][float] = 32 KB
    const int tid = threadIdx.x;
    const long row0 = (long)blockIdx.x * RPB;

    // chunk c: row = row0 + c/CPR, start = row*4096 + (c%CPR)*CHUNK  (CPR==2)
#define CS(c) (((row0 + ((c) >> 1)) << 12) + (long)(((c) & 1) * CHUNK))

    stage_chunk(lds[0][0], lds[0][1], s1, s2, CS(0), tid);
    __syncthreads();

#pragma unroll 1
    for (int c = 0; c < NCHUNK; ++c) {
        const int cur = c & 1;
        if (c + 1 < NCHUNK)
            stage_chunk(lds[cur ^ 1][0], lds[cur ^ 1][1], s1, s2, CS(c + 1), tid);
        compute_chunk(lds[cur][0], lds[cur][1], s1, s2, out, CS(c), tid,
                      (c & 1) == 0, (c & 1) == 1);
        __syncthreads();   // drains vmcnt (next-buf DMA landed) + barrier
    }
#undef CS
}

extern "C" void kernel_launch(void* const* d_in, const int* in_sizes, int n_in,
                              void* d_out, int out_size, void* d_ws, size_t ws_size,
                              hipStream_t stream) {
    const float* s1 = (const float*)d_in[0];
    const float* s2 = (const float*)d_in[1];
    float* out = (float*)d_out;

    const long total = (long)in_sizes[0];        // B * N
    const int B = (int)(total / N_FIXED);        // 8192
    const int blocks = B / RPB;                  // 1024 -> exactly 4 blocks/CU

    ssim1d_kernel<<<blocks, BLK, 0, stream>>>(s1, s2, out);
}